// Round 1
// 916.158 us; speedup vs baseline: 1.0250x; 1.0250x over previous
//
#include <hip/hip_runtime.h>

// InbucketPoolingLayer: per-instance bbox -> 40^3 voxel id -> stable counting
// sort by (inst, vox) -> pair consecutive sorted points -> mean pool.
//
// Stable sort strategy (keys are 19-bit, avg ~2 points/key):
//   1. histogram over K = B*64000 keys (atomicAdd)
//   2. exclusive scan of histogram (2-kernel chunked scan; chunk carry kept in
//      csums and folded into consumers instead of a 3rd pass)
//   3. unordered scatter into per-key segments (atomic ticket directly on hist)
//   4. per-key insertion sort of indices => exact stable order
//      (+ fused unpool_ind scatter + reduced_sep write)
//   5. fused feat+coord mean-pool gather pass
//
// Numerics match JAX bitwise: (c-lo)/fmaxf(hi-lo,1e-12f); (int)(u*40.0f); clamp.
// min/max are order-independent; (a+b)*0.5f == segment_sum/2 exactly.

#define VOXA 40
#define VOX3 64000
#define SCAN_CHUNK 2048

typedef float f4 __attribute__((ext_vector_type(4)));

__device__ __forceinline__ int inst_of(int i, const int* __restrict__ seps, int B) {
  // searchsorted(seps, i, side='right'): first idx with seps[idx] > i
  int lo = 0, hi = B;
  while (lo < hi) { int m = (lo + hi) >> 1; if (seps[m] > i) hi = m; else lo = m + 1; }
  return lo;
}

__device__ __forceinline__ int inst_of_s(int i, const int* s, int B) {
  int lo = 0, hi = B;
  while (lo < hi) { int m = (lo + hi) >> 1; if (s[m] > i) hi = m; else lo = m + 1; }
  return lo;
}

// monotonic float<->uint mapping so atomicMin/Max on unsigned give float min/max
__device__ __forceinline__ unsigned fmap(float f) {
  unsigned u = __float_as_uint(f);
  return (u & 0x80000000u) ? ~u : (u | 0x80000000u);
}
__device__ __forceinline__ float funmap(unsigned u) {
  unsigned b = (u & 0x80000000u) ? (u ^ 0x80000000u) : ~u;
  return __uint_as_float(b);
}

__global__ void k_init(int* hist, unsigned* bbox, int K, int B3) {
  int i = blockIdx.x * blockDim.x + threadIdx.x;
  if (i < K) hist[i] = 0;
  if (i < B3) { bbox[i] = 0xFFFFFFFFu; bbox[B3 + i] = 0u; }  // min-mapped=+inf, max-mapped=-inf
}

__global__ void k_bbox(const float* __restrict__ coords, const int* __restrict__ seps,
                       int N, int B, unsigned* __restrict__ bbox) {
  const int CH = 1024;
  int cs = blockIdx.x * CH;
  if (cs >= N) return;
  int ce = min(cs + CH, N);
  __shared__ int uni;
  int t = threadIdx.x;
  if (t == 0) {
    int i0 = inst_of(cs, seps, B);
    int i1 = inst_of(ce - 1, seps, B);
    uni = (i0 == i1) ? i0 : -1;
  }
  __syncthreads();
  if (uni >= 0) {
    float mn0 = 3.4e38f, mn1 = 3.4e38f, mn2 = 3.4e38f;
    float mx0 = -3.4e38f, mx1 = -3.4e38f, mx2 = -3.4e38f;
    for (int i = cs + t; i < ce; i += 256) {
      float c0 = coords[i * 3 + 0], c1 = coords[i * 3 + 1], c2 = coords[i * 3 + 2];
      mn0 = fminf(mn0, c0); mn1 = fminf(mn1, c1); mn2 = fminf(mn2, c2);
      mx0 = fmaxf(mx0, c0); mx1 = fmaxf(mx1, c1); mx2 = fmaxf(mx2, c2);
    }
    __shared__ float sm[6][256];
    sm[0][t] = mn0; sm[1][t] = mn1; sm[2][t] = mn2;
    sm[3][t] = mx0; sm[4][t] = mx1; sm[5][t] = mx2;
    __syncthreads();
    for (int s = 128; s > 0; s >>= 1) {
      if (t < s) {
        sm[0][t] = fminf(sm[0][t], sm[0][t + s]);
        sm[1][t] = fminf(sm[1][t], sm[1][t + s]);
        sm[2][t] = fminf(sm[2][t], sm[2][t + s]);
        sm[3][t] = fmaxf(sm[3][t], sm[3][t + s]);
        sm[4][t] = fmaxf(sm[4][t], sm[4][t + s]);
        sm[5][t] = fmaxf(sm[5][t], sm[5][t + s]);
      }
      __syncthreads();
    }
    if (t == 0) {
      int b = uni;
      atomicMin(&bbox[b * 3 + 0], fmap(sm[0][0]));
      atomicMin(&bbox[b * 3 + 1], fmap(sm[1][0]));
      atomicMin(&bbox[b * 3 + 2], fmap(sm[2][0]));
      atomicMax(&bbox[B * 3 + b * 3 + 0], fmap(sm[3][0]));
      atomicMax(&bbox[B * 3 + b * 3 + 1], fmap(sm[4][0]));
      atomicMax(&bbox[B * 3 + b * 3 + 2], fmap(sm[5][0]));
    }
  } else {
    // chunk straddles an instance boundary (rare): per-point atomics
    for (int i = cs + t; i < ce; i += 256) {
      int b = inst_of(i, seps, B);
      for (int d = 0; d < 3; ++d) {
        float c = coords[i * 3 + d];
        atomicMin(&bbox[b * 3 + d], fmap(c));
        atomicMax(&bbox[B * 3 + b * 3 + d], fmap(c));
      }
    }
  }
}

__global__ void k_key(const float* __restrict__ coords, const int* __restrict__ seps,
                      int N, int B, const unsigned* __restrict__ bbox,
                      int* __restrict__ key, int* __restrict__ hist) {
  __shared__ float lo[192], hi[192];  // supports B <= 64
  __shared__ int ssep[64];
  int t = threadIdx.x;
  if (t < 3 * B) { lo[t] = funmap(bbox[t]); hi[t] = funmap(bbox[3 * B + t]); }
  if (t < B) ssep[t] = seps[t];
  __syncthreads();
  int i = blockIdx.x * blockDim.x + t;
  if (i >= N) return;
  int b = inst_of_s(i, ssep, B);
  int q[3];
#pragma unroll
  for (int d = 0; d < 3; ++d) {
    float c = coords[i * 3 + d];
    float l = lo[b * 3 + d];
    float u = (c - l) / fmaxf(hi[b * 3 + d] - l, 1e-12f);  // IEEE f32 div, matches XLA
    int qi = (int)(u * 40.0f);                             // trunc == astype(int32)
    q[d] = min(max(qi, 0), VOXA - 1);
  }
  int k = ((q[0] * VOXA + q[1]) * VOXA + q[2]) + b * VOX3;
  key[i] = k;
  atomicAdd(&hist[k], 1);
}

__global__ void k_scan1(int* __restrict__ hist, int* __restrict__ csums, int K) {
  __shared__ int s[256];
  int t = threadIdx.x;
  int base = blockIdx.x * SCAN_CHUNK + t * 8;
  int v[8];
  int run = 0;
#pragma unroll
  for (int j = 0; j < 8; ++j) {
    int idx = base + j;
    int x = (idx < K) ? hist[idx] : 0;
    v[j] = run;   // local exclusive
    run += x;
  }
  s[t] = run;
  __syncthreads();
  for (int off = 1; off < 256; off <<= 1) {
    int x = (t >= off) ? s[t - off] : 0;
    __syncthreads();
    s[t] += x;
    __syncthreads();
  }
  int excl = s[t] - run;
#pragma unroll
  for (int j = 0; j < 8; ++j) {
    int idx = base + j;
    if (idx < K) hist[idx] = excl + v[j];
  }
  if (t == 255) csums[blockIdx.x] = s[255];
}

__global__ void k_scan2(int* csums, int nChunks) {
  __shared__ int s[256];
  int t = threadIdx.x;
  int carry = 0;
  for (int base = 0; base < nChunks; base += 256) {
    int idx = base + t;
    int v = (idx < nChunks) ? csums[idx] : 0;
    s[t] = v;
    __syncthreads();
    for (int off = 1; off < 256; off <<= 1) {
      int x = (t >= off) ? s[t - off] : 0;
      __syncthreads();
      s[t] += x;
      __syncthreads();
    }
    if (idx < nChunks) csums[idx] = carry + s[t] - v;  // exclusive
    int total = s[255];
    __syncthreads();
    carry += total;
  }
}

// Ticket-scatter. Atomics run directly on hist (chunk-local exclusive starts);
// global position = local ticket + chunk carry. After this kernel,
// hist[k] + csums[k/CHUNK] == global END of key k's segment.
__global__ void k_place(const int* __restrict__ key, int* __restrict__ hist,
                        const int* __restrict__ csums, int* __restrict__ order, int N) {
  int i = blockIdx.x * blockDim.x + threadIdx.x;
  if (i >= N) return;
  int k = key[i];
  int p = atomicAdd(&hist[k], 1) + csums[k / SCAN_CHUNK];
  order[p] = i;
}

// Per-key insertion sort => exact stable order. Fused: unpool_ind scatter
// (one owner thread per key, positions partition [0,N) => no race) and the
// reduced_sep tail write.
__global__ void k_fix(const int* __restrict__ hist, const int* __restrict__ csums,
                      int* __restrict__ order, float* __restrict__ outu,
                      const int* __restrict__ seps, float* __restrict__ out_sep,
                      int K, int N, int B) {
  int k = blockIdx.x * blockDim.x + threadIdx.x;
  if (k < B) out_sep[k] = (float)(seps[k] / 2);  // reduced_sep as float
  if (k >= K) return;
  int e = hist[k] + csums[k / SCAN_CHUNK];
  int s = (k == 0) ? 0 : (hist[k - 1] + csums[(k - 1) / SCAN_CHUNK]);
  for (int a = s + 1; a < e; ++a) {
    int v = order[a];
    int b = a - 1;
    while (b >= s && order[b] > v) { order[b + 1] = order[b]; --b; }
    order[b + 1] = v;
  }
  for (int p = s; p < e; ++p) outu[order[p]] = (float)(p >> 1);  // unpool_ind
}

// Fused feat + coord mean pooling. 32 lanes per output row (128 feats = 32 f4);
// lane c==0 of each row group additionally pools the 3 coords.
__global__ void k_out_fused(const f4* __restrict__ feat4, const float* __restrict__ coords,
                            const int* __restrict__ order, int RN,
                            float* __restrict__ out_coord, f4* __restrict__ outf) {
  int tid = blockIdx.x * blockDim.x + threadIdx.x;
  if (tid >= RN * 32) return;
  int r = tid >> 5, c = tid & 31;
  int2 ab = ((const int2*)order)[r];
  int a = ab.x, b = ab.y;
  f4 va = __builtin_nontemporal_load(&feat4[(size_t)a * 32 + c]);
  f4 vb = __builtin_nontemporal_load(&feat4[(size_t)b * 32 + c]);
  f4 o = (va + vb) * 0.5f;
  __builtin_nontemporal_store(o, &outf[tid]);
  if (c == 0) {
    out_coord[r * 3 + 0] = (coords[a * 3 + 0] + coords[b * 3 + 0]) * 0.5f;
    out_coord[r * 3 + 1] = (coords[a * 3 + 1] + coords[b * 3 + 1]) * 0.5f;
    out_coord[r * 3 + 2] = (coords[a * 3 + 2] + coords[b * 3 + 2]) * 0.5f;
  }
}

// Scalar fallback (FE != 128 or misaligned feat output).
__global__ void k_out_fused_scalar(const float* __restrict__ feat, const float* __restrict__ coords,
                                   const int* __restrict__ order, int RN, int FE,
                                   float* __restrict__ out_coord, float* __restrict__ outf) {
  int tid = blockIdx.x * blockDim.x + threadIdx.x;
  if (tid >= RN * FE) return;
  int r = tid / FE, c = tid % FE;
  int a = order[2 * r], b = order[2 * r + 1];
  outf[tid] = (feat[(size_t)a * FE + c] + feat[(size_t)b * FE + c]) * 0.5f;
  if (c == 0) {
    out_coord[r * 3 + 0] = (coords[a * 3 + 0] + coords[b * 3 + 0]) * 0.5f;
    out_coord[r * 3 + 1] = (coords[a * 3 + 1] + coords[b * 3 + 1]) * 0.5f;
    out_coord[r * 3 + 2] = (coords[a * 3 + 2] + coords[b * 3 + 2]) * 0.5f;
  }
}

extern "C" void kernel_launch(void* const* d_in, const int* in_sizes, int n_in,
                              void* d_out, int out_size, void* d_ws, size_t ws_size,
                              hipStream_t stream) {
  const float* coords = (const float*)d_in[0];
  const float* feat   = (const float*)d_in[1];
  const int*   seps   = (const int*)d_in[2];

  const int N  = in_sizes[0] / 3;
  const int B  = in_sizes[2];
  const int FE = in_sizes[1] / N;  // 128
  const int RN = N / 2;
  const int K  = B * VOX3;
  const int nChunks = (K + SCAN_CHUNK - 1) / SCAN_CHUNK;

  // workspace layout (ints): hist[K] | csums[pad] | bbox[6B] | key[N] | order[N]
  int* hist      = (int*)d_ws;
  int* csums     = hist + K;
  unsigned* bbox = (unsigned*)(csums + ((nChunks + 255) & ~255));
  int* key       = (int*)(bbox + 6 * B);
  int* order     = key + N;

  float* out        = (float*)d_out;
  float* out_coord  = out;                                   // RN*3
  float* out_sep    = out + (size_t)RN * 3;                  // B
  float* out_feat   = out + (size_t)RN * 3 + B;              // RN*FE
  float* out_unpool = out_feat + (size_t)RN * FE;            // N

  const int blk = 256;
  k_init<<<(K + blk - 1) / blk, blk, 0, stream>>>(hist, bbox, K, 3 * B);
  k_bbox<<<(N + 1023) / 1024, 256, 0, stream>>>(coords, seps, N, B, bbox);
  k_key<<<(N + blk - 1) / blk, blk, 0, stream>>>(coords, seps, N, B, bbox, key, hist);
  k_scan1<<<nChunks, 256, 0, stream>>>(hist, csums, K);
  k_scan2<<<1, 256, 0, stream>>>(csums, nChunks);
  k_place<<<(N + blk - 1) / blk, blk, 0, stream>>>(key, hist, csums, order, N);
  k_fix<<<(K + blk - 1) / blk, blk, 0, stream>>>(hist, csums, order, out_unpool,
                                                 seps, out_sep, K, N, B);

  bool vec_ok = (FE == 128) && ((((size_t)RN * 3 + B) & 3) == 0);
  if (vec_ok) {
    k_out_fused<<<((RN * 32) + blk - 1) / blk, blk, 0, stream>>>(
        (const f4*)feat, coords, order, RN, out_coord, (f4*)out_feat);
  } else {
    k_out_fused_scalar<<<((RN * FE) + blk - 1) / blk, blk, 0, stream>>>(
        feat, coords, order, RN, FE, out_coord, out_feat);
  }
}